// Round 1
// baseline (571.283 us; speedup 1.0000x reference)
//
#include <hip/hip_runtime.h>
#include <math.h>

// Problem constants: B=4, C=64, H=W=64 -> N=4096. All fp32.
#define T_N 4096
#define T_C 64
#define T_B 4

// ---------------------------------------------------------------------------
// Kernel 1: fused QKV projection.  q[b,o,n] = sum_c Wq[o,c]*x[b,c,n] + bq[o]
// grid (N/64, B), block 256. Weights staged in LDS (48 KB); x read directly
// from global (each 256B row is broadcast-reused by 16 thread-groups, L1-hit).
// Each thread computes a 4(o) x 4(n) register tile for all three projections.
// ---------------------------------------------------------------------------
__global__ __launch_bounds__(256) void qkv_kernel(
    const float* __restrict__ x,
    const float* __restrict__ Wq, const float* __restrict__ bq,
    const float* __restrict__ Wk, const float* __restrict__ bk,
    const float* __restrict__ Wv, const float* __restrict__ bv,
    float* __restrict__ q, float* __restrict__ k, float* __restrict__ v)
{
    __shared__ __align__(16) float wqs[64 * 64];
    __shared__ __align__(16) float wks[64 * 64];
    __shared__ __align__(16) float wvs[64 * 64];

    const int tid = threadIdx.x;
    const int n0  = blockIdx.x * 64;
    const int b   = blockIdx.y;
    const float* xb = x + (size_t)b * T_C * T_N;

    #pragma unroll
    for (int idx = tid; idx < 4096; idx += 256) {
        wqs[idx] = Wq[idx];
        wks[idx] = Wk[idx];
        wvs[idx] = Wv[idx];
    }

    const int oi = (tid >> 4) * 4;   // output-channel base: 0..60
    const int nj = (tid & 15) * 4;   // pixel base within 64-tile

    float aq[4][4], ak[4][4], av[4][4];
    #pragma unroll
    for (int u = 0; u < 4; ++u) {
        const float bqv = bq[oi + u], bkv = bk[oi + u], bvv = bv[oi + u];
        #pragma unroll
        for (int w = 0; w < 4; ++w) { aq[u][w] = bqv; ak[u][w] = bkv; av[u][w] = bvv; }
    }
    __syncthreads();

    #pragma unroll 4
    for (int c = 0; c < 64; ++c) {
        const float4 xv = *(const float4*)&xb[c * T_N + n0 + nj];
        const float xa[4] = {xv.x, xv.y, xv.z, xv.w};
        #pragma unroll
        for (int u = 0; u < 4; ++u) {
            const float wq_ = wqs[(oi + u) * 64 + c];
            const float wk_ = wks[(oi + u) * 64 + c];
            const float wv_ = wvs[(oi + u) * 64 + c];
            #pragma unroll
            for (int w = 0; w < 4; ++w) {
                aq[u][w] = fmaf(wq_, xa[w], aq[u][w]);
                ak[u][w] = fmaf(wk_, xa[w], ak[u][w]);
                av[u][w] = fmaf(wv_, xa[w], av[u][w]);
            }
        }
    }

    #pragma unroll
    for (int u = 0; u < 4; ++u) {
        const size_t off = ((size_t)b * T_C + (oi + u)) * T_N + n0 + nj;
        *(float4*)&q[off] = make_float4(aq[u][0], aq[u][1], aq[u][2], aq[u][3]);
        *(float4*)&k[off] = make_float4(ak[u][0], ak[u][1], ak[u][2], ak[u][3]);
        *(float4*)&v[off] = make_float4(av[u][0], av[u][1], av[u][2], av[u][3]);
    }
}

// ---------------------------------------------------------------------------
// Kernel 2: flash-attention (fp32, online softmax). One block per
// (batch, 64-query tile): grid (64, 4), block 256 (4 waves).
//   S[r][m] = sum_c Q[c][r]*K[c][m]; P = exp(S - m_row); O = V P^T; out = O/l
// Thread (ti,tj): owns S rows 4ti..+3 / cols 4tj..+3 in phase 1, and
// O channels 4ti..+3 / queries 4tj..+3 in phase 2. Row-state reductions stay
// inside one 16-lane shuffle group (rows of a group owned by a single wave).
// LDS: qs 16K + kv 17K (K as [c][m], then V transposed [m][c]) + ps 17K.
// ---------------------------------------------------------------------------
__global__ __launch_bounds__(256) void attn_kernel(
    const float* __restrict__ q, const float* __restrict__ k,
    const float* __restrict__ v, float* __restrict__ out)
{
    __shared__ __align__(16) float qs[64][64];   // [c][r]
    __shared__ __align__(16) float kv[64][68];   // K: [c][m] ; then V: [m][c]
    __shared__ __align__(16) float ps[64][68];   // [m][r]
    __shared__ float m_state[64], l_state[64], a_state[64];

    const int tid = threadIdx.x;
    const int n0  = blockIdx.x * 64;
    const int b   = blockIdx.y;
    const size_t base = (size_t)b * T_C * T_N;
    const float* qb = q + base;
    const float* kb = k + base;
    const float* vb = v + base;

    const int ti = (tid >> 4) * 4;   // S-row / O-channel base
    const int tj = (tid & 15) * 4;   // S-col / O-query base

    if (tid < 64) { m_state[tid] = -INFINITY; l_state[tid] = 0.f; }

    for (int idx = tid; idx < 4096; idx += 256) {
        const int c = idx >> 6, r = idx & 63;
        qs[c][r] = qb[c * T_N + n0 + r];
    }

    float O[4][4] = {{0.f}};
    __syncthreads();

    for (int kt = 0; kt < 64; ++kt) {
        const int m0 = kt * 64;

        // --- stage K tile [c][m] ---
        for (int idx = tid; idx < 4096; idx += 256) {
            const int c = idx >> 6, m = idx & 63;
            kv[c][m] = kb[c * T_N + m0 + m];
        }
        __syncthreads();

        // --- S = Q^T K (4x4 register tile) ---
        float S[4][4] = {{0.f}};
        #pragma unroll 4
        for (int c = 0; c < 64; ++c) {
            const float4 q4 = *(const float4*)&qs[c][ti];
            const float4 k4 = *(const float4*)&kv[c][tj];
            const float qa[4] = {q4.x, q4.y, q4.z, q4.w};
            const float ka[4] = {k4.x, k4.y, k4.z, k4.w};
            #pragma unroll
            for (int u = 0; u < 4; ++u)
                #pragma unroll
                for (int w = 0; w < 4; ++w)
                    S[u][w] = fmaf(qa[u], ka[w], S[u][w]);
        }

        // --- online softmax over the tile (row state in LDS; the 16 lanes of
        //     a row group live in one wave -> lockstep read-then-write is safe)
        #pragma unroll
        for (int u = 0; u < 4; ++u) {
            float mx = fmaxf(fmaxf(S[u][0], S[u][1]), fmaxf(S[u][2], S[u][3]));
            #pragma unroll
            for (int off = 1; off < 16; off <<= 1)
                mx = fmaxf(mx, __shfl_xor(mx, off));
            const float m_old = m_state[ti + u];
            const float m_new = fmaxf(m_old, mx);
            const float alpha = __expf(m_old - m_new);
            float sum = 0.f;
            #pragma unroll
            for (int w = 0; w < 4; ++w) {
                const float p = __expf(S[u][w] - m_new);
                S[u][w] = p;
                sum += p;
            }
            #pragma unroll
            for (int off = 1; off < 16; off <<= 1)
                sum += __shfl_xor(sum, off);
            if ((tid & 15) == 0) {
                m_state[ti + u] = m_new;
                l_state[ti + u] = alpha * l_state[ti + u] + sum;
                a_state[ti + u] = alpha;
            }
        }

        // --- write P transposed: ps[m][r] ---
        #pragma unroll
        for (int w = 0; w < 4; ++w)
            *(float4*)&ps[tj + w][ti] =
                make_float4(S[0][w], S[1][w], S[2][w], S[3][w]);

        __syncthreads();

        // --- stage V tile transposed [m][c] (reuses kv buffer) ---
        for (int idx = tid; idx < 4096; idx += 256) {
            const int c = idx >> 6, m = idx & 63;
            kv[m][c] = vb[c * T_N + m0 + m];
        }
        __syncthreads();

        // --- O = alpha*O + V P^T ---
        float al[4];
        #pragma unroll
        for (int w = 0; w < 4; ++w) al[w] = a_state[tj + w];
        #pragma unroll
        for (int u = 0; u < 4; ++u)
            #pragma unroll
            for (int w = 0; w < 4; ++w)
                O[u][w] *= al[w];

        #pragma unroll 4
        for (int m = 0; m < 64; ++m) {
            const float4 v4 = *(const float4*)&kv[m][ti];
            const float4 p4 = *(const float4*)&ps[m][tj];
            const float va[4] = {v4.x, v4.y, v4.z, v4.w};
            const float pa[4] = {p4.x, p4.y, p4.z, p4.w};
            #pragma unroll
            for (int u = 0; u < 4; ++u)
                #pragma unroll
                for (int w = 0; w < 4; ++w)
                    O[u][w] = fmaf(va[u], pa[w], O[u][w]);
        }
        __syncthreads();
    }

    const float li[4] = {1.f / l_state[tj + 0], 1.f / l_state[tj + 1],
                         1.f / l_state[tj + 2], 1.f / l_state[tj + 3]};
    #pragma unroll
    for (int u = 0; u < 4; ++u) {
        const size_t off = base + (size_t)(ti + u) * T_N + n0 + tj;
        *(float4*)&out[off] = make_float4(O[u][0] * li[0], O[u][1] * li[1],
                                          O[u][2] * li[2], O[u][3] * li[3]);
    }
}

// ---------------------------------------------------------------------------
extern "C" void kernel_launch(void* const* d_in, const int* in_sizes, int n_in,
                              void* d_out, int out_size, void* d_ws, size_t ws_size,
                              hipStream_t stream) {
    const float* x  = (const float*)d_in[0];
    const float* Wq = (const float*)d_in[1];
    const float* bq = (const float*)d_in[2];
    const float* Wk = (const float*)d_in[3];
    const float* bk = (const float*)d_in[4];
    const float* Wv = (const float*)d_in[5];
    const float* bv = (const float*)d_in[6];
    float* outp = (float*)d_out;

    // Workspace: q, k, v each B*C*N floats (4 MB) -> 12 MB total.
    float* qw = (float*)d_ws;
    float* kw = qw + (size_t)T_B * T_C * T_N;
    float* vw = kw + (size_t)T_B * T_C * T_N;

    qkv_kernel<<<dim3(T_N / 64, T_B), 256, 0, stream>>>(
        x, Wq, bq, Wk, bk, Wv, bv, qw, kw, vw);
    attn_kernel<<<dim3(T_N / 64, T_B), 256, 0, stream>>>(qw, kw, vw, outp);
}

// Round 2
// 232.837 us; speedup vs baseline: 2.4536x; 2.4536x over previous
//
#include <hip/hip_runtime.h>
#include <math.h>

// B=4, C=64, H=W=64 -> N=4096. fp32 in/out; bf16 hi/lo MFMA internally.
#define T_N 4096
#define T_C 64
#define T_B 4

typedef __attribute__((ext_vector_type(8))) short bf16x8;   // 8 bf16 (4 VGPRs)
typedef __attribute__((ext_vector_type(4))) float f32x4;    // MFMA accumulator

__device__ inline unsigned short f2bf(float f) {   // RNE float->bf16
    union { float f; unsigned u; } x; x.f = f;
    unsigned r = x.u + 0x7fffu + ((x.u >> 16) & 1u);
    return (unsigned short)(r >> 16);
}
__device__ inline float bf2f(unsigned short h) {
    union { unsigned u; float f; } x; x.u = ((unsigned)h) << 16;
    return x.f;
}

// ---------------------------------------------------------------------------
// Kernel 1: fused QKV projection -> bf16 hi/lo outputs.
//   qt_hi/qt_lo, kt_hi/kt_lo: (B, N, C) layout (query/key-major, channels contig)
//   vb:                       (B, C, N) layout (channel-major, pixels contig)
// grid (N/64, B), block 256; weights in LDS; 4(o)x4(n) register tile/thread.
// ---------------------------------------------------------------------------
__global__ __launch_bounds__(256) void qkv_kernel(
    const float* __restrict__ x,
    const float* __restrict__ Wq, const float* __restrict__ bq,
    const float* __restrict__ Wk, const float* __restrict__ bk,
    const float* __restrict__ Wv, const float* __restrict__ bv,
    unsigned short* __restrict__ qt_hi, unsigned short* __restrict__ qt_lo,
    unsigned short* __restrict__ kt_hi, unsigned short* __restrict__ kt_lo,
    unsigned short* __restrict__ vb)
{
    __shared__ __align__(16) float wqs[64 * 64];
    __shared__ __align__(16) float wks[64 * 64];
    __shared__ __align__(16) float wvs[64 * 64];

    const int tid = threadIdx.x;
    const int n0  = blockIdx.x * 64;
    const int b   = blockIdx.y;
    const float* xb = x + (size_t)b * T_C * T_N;

    #pragma unroll
    for (int idx = tid; idx < 4096; idx += 256) {
        wqs[idx] = Wq[idx];
        wks[idx] = Wk[idx];
        wvs[idx] = Wv[idx];
    }

    const int oi = (tid >> 4) * 4;   // output-channel base
    const int nj = (tid & 15) * 4;   // pixel base within 64-tile

    float aq[4][4], ak[4][4], av[4][4];
    #pragma unroll
    for (int u = 0; u < 4; ++u) {
        const float bqv = bq[oi + u], bkv = bk[oi + u], bvv = bv[oi + u];
        #pragma unroll
        for (int w = 0; w < 4; ++w) { aq[u][w] = bqv; ak[u][w] = bkv; av[u][w] = bvv; }
    }
    __syncthreads();

    #pragma unroll 4
    for (int c = 0; c < 64; ++c) {
        const float4 xv = *(const float4*)&xb[c * T_N + n0 + nj];
        const float xa[4] = {xv.x, xv.y, xv.z, xv.w};
        #pragma unroll
        for (int u = 0; u < 4; ++u) {
            const float wq_ = wqs[(oi + u) * 64 + c];
            const float wk_ = wks[(oi + u) * 64 + c];
            const float wv_ = wvs[(oi + u) * 64 + c];
            #pragma unroll
            for (int w = 0; w < 4; ++w) {
                aq[u][w] = fmaf(wq_, xa[w], aq[u][w]);
                ak[u][w] = fmaf(wk_, xa[w], ak[u][w]);
                av[u][w] = fmaf(wv_, xa[w], av[u][w]);
            }
        }
    }

    union U4 { ushort4 v; unsigned short s[4]; };

    // Q/K transposed hi/lo stores: row = pixel, cols = channels oi..oi+3
    #pragma unroll
    for (int w = 0; w < 4; ++w) {
        U4 hq, lq, hk, lk;
        #pragma unroll
        for (int u = 0; u < 4; ++u) {
            const float fq = aq[u][w];
            const unsigned short hqb = f2bf(fq);
            hq.s[u] = hqb; lq.s[u] = f2bf(fq - bf2f(hqb));
            const float fk = ak[u][w];
            const unsigned short hkb = f2bf(fk);
            hk.s[u] = hkb; lk.s[u] = f2bf(fk - bf2f(hkb));
        }
        const size_t off = ((size_t)b * T_N + n0 + nj + w) * 64 + oi;
        *(ushort4*)&qt_hi[off] = hq.v;
        *(ushort4*)&qt_lo[off] = lq.v;
        *(ushort4*)&kt_hi[off] = hk.v;
        *(ushort4*)&kt_lo[off] = lk.v;
    }
    // V natural layout bf16
    #pragma unroll
    for (int u = 0; u < 4; ++u) {
        U4 hv;
        #pragma unroll
        for (int w = 0; w < 4; ++w) hv.s[w] = f2bf(av[u][w]);
        *(ushort4*)&vb[((size_t)(b * 64 + oi + u)) * T_N + n0 + nj] = hv.v;
    }
}

// ---------------------------------------------------------------------------
// Kernel 2: flash attention via MFMA 16x16x32 bf16.
// grid (64,4), block 256 (4 waves). Wave w owns query rows 16w..16w+15.
// S = qh*kh + ql*kh + qh*kl (hi/lo fp32-accurate); online softmax in base-e;
// P round-trips LDS (C-layout -> B-operand layout); O += V*P^T via MFMA.
// LDS rows padded to 72 shorts (144 B) -> 2-way bank aliasing only (free).
// ---------------------------------------------------------------------------
__global__ __launch_bounds__(256) void attn_kernel(
    const unsigned short* __restrict__ qt_hi, const unsigned short* __restrict__ qt_lo,
    const unsigned short* __restrict__ kt_hi, const unsigned short* __restrict__ kt_lo,
    const unsigned short* __restrict__ vb, float* __restrict__ out)
{
    __shared__ __align__(16) unsigned short qs_hi[64 * 72];
    __shared__ __align__(16) unsigned short qs_lo[64 * 72];
    __shared__ __align__(16) unsigned short ks_hi[64 * 72];
    __shared__ __align__(16) unsigned short ks_lo[64 * 72];
    __shared__ __align__(16) unsigned short vs[64 * 72];
    __shared__ __align__(16) unsigned short ps[64 * 72];
    __shared__ float as_l[64], ls_l[64];

    const int tid  = threadIdx.x;
    const int n0   = blockIdx.x * 64;
    const int b    = blockIdx.y;
    const int wv   = tid >> 6;       // wave 0..3
    const int lane = tid & 63;
    const int quad = lane >> 4;      // 0..3
    const int col  = lane & 15;      // 0..15

    const size_t bN = (size_t)b * T_N;

    // stage Q tile (hi/lo), rows = queries, cols = channels
    for (int i = tid; i < 512; i += 256) {
        const int row = i >> 3, cc = i & 7;
        *(float4*)&qs_hi[row * 72 + cc * 8] =
            *(const float4*)&qt_hi[(bN + n0 + row) * 64 + cc * 8];
        *(float4*)&qs_lo[row * 72 + cc * 8] =
            *(const float4*)&qt_lo[(bN + n0 + row) * 64 + cc * 8];
    }
    __syncthreads();

    // persistent Q A-fragments: A[m=col][k = s*32 + quad*8 + j]
    bf16x8 qh[2], ql[2];
    #pragma unroll
    for (int s = 0; s < 2; ++s) {
        qh[s] = *(const bf16x8*)&qs_hi[(wv * 16 + col) * 72 + s * 32 + quad * 8];
        ql[s] = *(const bf16x8*)&qs_lo[(wv * 16 + col) * 72 + s * 32 + quad * 8];
    }

    f32x4 O[4];
    #pragma unroll
    for (int t = 0; t < 4; ++t) O[t] = (f32x4){0.f, 0.f, 0.f, 0.f};
    float m_st[4], l_st[4];
    #pragma unroll
    for (int r = 0; r < 4; ++r) { m_st[r] = -INFINITY; l_st[r] = 0.f; }

    for (int kt = 0; kt < 64; ++kt) {
        const int m0 = kt * 64;
        __syncthreads();   // previous iteration's reads of ks/vs done
        for (int i = tid; i < 512; i += 256) {
            const int row = i >> 3, cc = i & 7;
            *(float4*)&ks_hi[row * 72 + cc * 8] =
                *(const float4*)&kt_hi[(bN + m0 + row) * 64 + cc * 8];
            *(float4*)&ks_lo[row * 72 + cc * 8] =
                *(const float4*)&kt_lo[(bN + m0 + row) * 64 + cc * 8];
            *(float4*)&vs[row * 72 + cc * 8] =
                *(const float4*)&vb[((size_t)(b * 64 + row)) * T_N + m0 + cc * 8];
        }
        __syncthreads();

        // --- S = Q^T K : 4 key sub-tiles, hi/lo 3-MFMA split ---
        f32x4 acc[4];
        #pragma unroll
        for (int t = 0; t < 4; ++t) acc[t] = (f32x4){0.f, 0.f, 0.f, 0.f};
        #pragma unroll
        for (int s = 0; s < 2; ++s) {
            #pragma unroll
            for (int t = 0; t < 4; ++t) {
                const bf16x8 bh =
                    *(const bf16x8*)&ks_hi[(t * 16 + col) * 72 + s * 32 + quad * 8];
                const bf16x8 bl =
                    *(const bf16x8*)&ks_lo[(t * 16 + col) * 72 + s * 32 + quad * 8];
                acc[t] = __builtin_amdgcn_mfma_f32_16x16x32_bf16(qh[s], bh, acc[t], 0, 0, 0);
                acc[t] = __builtin_amdgcn_mfma_f32_16x16x32_bf16(ql[s], bh, acc[t], 0, 0, 0);
                acc[t] = __builtin_amdgcn_mfma_f32_16x16x32_bf16(qh[s], bl, acc[t], 0, 0, 0);
            }
        }

        // --- online softmax; lane holds S[q = 16w+quad*4+r][key = 16t+col] ---
        float alpha[4];
        #pragma unroll
        for (int r = 0; r < 4; ++r) {
            float mx = fmaxf(fmaxf(acc[0][r], acc[1][r]), fmaxf(acc[2][r], acc[3][r]));
            #pragma unroll
            for (int off = 1; off < 16; off <<= 1)
                mx = fmaxf(mx, __shfl_xor(mx, off));
            const float mnew = fmaxf(m_st[r], mx);
            alpha[r] = __expf(m_st[r] - mnew);
            float p[4], sum = 0.f;
            #pragma unroll
            for (int t = 0; t < 4; ++t) {
                p[t] = __expf(acc[t][r] - mnew);
                sum += p[t];
            }
            #pragma unroll
            for (int off = 1; off < 16; off <<= 1)
                sum += __shfl_xor(sum, off);
            l_st[r] = alpha[r] * l_st[r] + sum;
            m_st[r] = mnew;
            #pragma unroll
            for (int t = 0; t < 4; ++t)
                ps[(wv * 16 + quad * 4 + r) * 72 + t * 16 + col] = f2bf(p[t]);
        }
        if (col == 0) {
            #pragma unroll
            for (int r = 0; r < 4; ++r) as_l[wv * 16 + quad * 4 + r] = alpha[r];
        }

        // --- O = alpha*O + V P^T (wave-local ps/as_l; compiler waits lgkmcnt) ---
        const float al = as_l[wv * 16 + col];
        bf16x8 pf[2];
        #pragma unroll
        for (int s2 = 0; s2 < 2; ++s2)
            pf[s2] = *(const bf16x8*)&ps[(wv * 16 + col) * 72 + s2 * 32 + quad * 8];
        #pragma unroll
        for (int tc = 0; tc < 4; ++tc) {
            O[tc] *= al;
            #pragma unroll
            for (int s2 = 0; s2 < 2; ++s2) {
                const bf16x8 vf =
                    *(const bf16x8*)&vs[(tc * 16 + col) * 72 + s2 * 32 + quad * 8];
                O[tc] = __builtin_amdgcn_mfma_f32_16x16x32_bf16(vf, pf[s2], O[tc], 0, 0, 0);
            }
        }
    }

    // --- epilogue: divide by l, store. O element: c=16tc+quad*4+r, q=16w+col ---
    if (col == 0) {
        #pragma unroll
        for (int r = 0; r < 4; ++r) ls_l[wv * 16 + quad * 4 + r] = l_st[r];
    }
    const float inv = 1.f / ls_l[wv * 16 + col];
    #pragma unroll
    for (int tc = 0; tc < 4; ++tc) {
        #pragma unroll
        for (int r = 0; r < 4; ++r) {
            out[((size_t)(b * 64 + tc * 16 + quad * 4 + r)) * T_N + n0 + wv * 16 + col] =
                O[tc][r] * inv;
        }
    }
}

// ---------------------------------------------------------------------------
extern "C" void kernel_launch(void* const* d_in, const int* in_sizes, int n_in,
                              void* d_out, int out_size, void* d_ws, size_t ws_size,
                              hipStream_t stream) {
    const float* x  = (const float*)d_in[0];
    const float* Wq = (const float*)d_in[1];
    const float* bq = (const float*)d_in[2];
    const float* Wk = (const float*)d_in[3];
    const float* bk = (const float*)d_in[4];
    const float* Wv = (const float*)d_in[5];
    const float* bv = (const float*)d_in[6];
    float* outp = (float*)d_out;

    // ws: 5 bf16 arrays of B*N*C = 1,048,576 elems (2 MB) each -> 10 MB
    const size_t elems = (size_t)T_B * T_N * T_C;
    unsigned short* qt_hi = (unsigned short*)d_ws;
    unsigned short* qt_lo = qt_hi + elems;
    unsigned short* kt_hi = qt_lo + elems;
    unsigned short* kt_lo = kt_hi + elems;
    unsigned short* vbuf  = kt_lo + elems;

    qkv_kernel<<<dim3(T_N / 64, T_B), 256, 0, stream>>>(
        x, Wq, bq, Wk, bk, Wv, bv, qt_hi, qt_lo, kt_hi, kt_lo, vbuf);
    attn_kernel<<<dim3(T_N / 64, T_B), 256, 0, stream>>>(
        qt_hi, qt_lo, kt_hi, kt_lo, vbuf, outp);
}